// Round 1
// baseline (434.126 us; speedup 1.0000x reference)
//
#include <hip/hip_runtime.h>
#include <hip/hip_bf16.h>

typedef __attribute__((ext_vector_type(4))) float f32x4;
typedef __attribute__((ext_vector_type(8))) short bf16x8;

// Problem dims (fixed)
#define M_DIM 8192      // B*S = 4*2048
#define N_DIM 4096      // D_out
#define K_DIM 4096      // D_in
#define NH 8
#define R_DIM 16

__device__ __forceinline__ unsigned short f2bf(float f) {
  union { float f; unsigned int u; } v; v.f = f;
  unsigned int r = v.u + 0x7fffu + ((v.u >> 16) & 1u);  // RNE
  return (unsigned short)(r >> 16);
}

__device__ __forceinline__ void gll16(const void* gptr, void* lptr) {
  __builtin_amdgcn_global_load_lds(
      (const __attribute__((address_space(1))) void*)gptr,
      (__attribute__((address_space(3))) void*)lptr, 16, 0, 0);
}

// ---------------- Kernel 1: cast x (f32) -> bf16 ----------------
__global__ void k_cast_bf16(const float* __restrict__ in,
                            unsigned short* __restrict__ out, int n4) {
  int i = blockIdx.x * 256 + threadIdx.x;
  if (i >= n4) return;
  float4 v = reinterpret_cast<const float4*>(in)[i];
  ushort4 o;
  o.x = f2bf(v.x); o.y = f2bf(v.y); o.z = f2bf(v.z); o.w = f2bf(v.w);
  reinterpret_cast<ushort4*>(out)[i] = o;
}

// ---------------- Kernel 2: HA[h][q][d] = s[h] * sum_r H[h][q][r]*A[h][r][d] ----------------
// 8*16*1024 threads, each does one float4 chunk of d.
__global__ void k_ha(const float* __restrict__ A, const float* __restrict__ H,
                     const float* __restrict__ s, float* __restrict__ HA) {
  int idx = blockIdx.x * 256 + threadIdx.x;   // 0 .. 131071
  int dc = idx & 1023;                        // float4 chunk
  int q  = (idx >> 10) & 15;
  int h  = idx >> 14;
  const float* Ah = A + (long)h * R_DIM * K_DIM;
  const float* Hh = H + h * R_DIM * R_DIM + q * R_DIM;
  f32x4 acc = {0.f, 0.f, 0.f, 0.f};
  #pragma unroll
  for (int r = 0; r < R_DIM; ++r) {
    float hv = Hh[r];
    float4 av = reinterpret_cast<const float4*>(Ah + (long)r * K_DIM)[dc];
    acc.x += hv * av.x; acc.y += hv * av.y; acc.z += hv * av.z; acc.w += hv * av.w;
  }
  float sv = s[h];
  float4 o; o.x = acc.x * sv; o.y = acc.y * sv; o.z = acc.z * sv; o.w = acc.w * sv;
  reinterpret_cast<float4*>(HA + ((long)h * R_DIM + q) * K_DIM)[dc] = o;
}

// ---------------- Kernel 3: Weff = bf16(W + Bcat @ HA) ----------------
// Bcat[o][hq] = B[h][o][q]; block = 8 rows x 1024 cols.
__global__ void k_weff(const float* __restrict__ W, const float* __restrict__ Bm,
                       const float* __restrict__ HA, unsigned short* __restrict__ Weff) {
  __shared__ float bsh[8][128];
  int o0 = blockIdx.x * 8;
  int c4 = blockIdx.y * 256;   // float4 column base
  int t = threadIdx.x;
  for (int i = t; i < 1024; i += 256) {
    int r = i >> 7, hq = i & 127;
    int h = hq >> 4, q = hq & 15;
    bsh[r][hq] = Bm[((long)h * N_DIM + (o0 + r)) * R_DIM + q];
  }
  __syncthreads();
  int dc = c4 + t;
  f32x4 acc[8];
  #pragma unroll
  for (int r = 0; r < 8; ++r) {
    float4 w = reinterpret_cast<const float4*>(W + (long)(o0 + r) * K_DIM)[dc];
    acc[r].x = w.x; acc[r].y = w.y; acc[r].z = w.z; acc[r].w = w.w;
  }
  for (int hq = 0; hq < 128; ++hq) {
    float4 hv = reinterpret_cast<const float4*>(HA + (long)hq * K_DIM)[dc];
    #pragma unroll
    for (int r = 0; r < 8; ++r) {
      float bv = bsh[r][hq];
      acc[r].x += bv * hv.x; acc[r].y += bv * hv.y;
      acc[r].z += bv * hv.z; acc[r].w += bv * hv.w;
    }
  }
  #pragma unroll
  for (int r = 0; r < 8; ++r) {
    ushort4 ov;
    ov.x = f2bf(acc[r].x); ov.y = f2bf(acc[r].y);
    ov.z = f2bf(acc[r].z); ov.w = f2bf(acc[r].w);
    reinterpret_cast<ushort4*>(Weff + (long)(o0 + r) * K_DIM)[dc] = ov;
  }
}

// ---------------- Kernel 4: C[M][N] = Abf[M][K] @ Bbf[N][K]^T + bias ----------------
// m97 structure: 128x128 tile, BK=32, 4 waves (2x2), global_load_lds width 16.
__global__ __launch_bounds__(256)
void k_gemm(const unsigned short* __restrict__ A,   // x bf16 [M][K]
            const unsigned short* __restrict__ Bw,  // Weff bf16 [N][K]
            const float* __restrict__ bias,         // [N]
            float* __restrict__ C) {                // [M][N] f32
  constexpr int BM = 128, BN = 128, BK = 32;
  __shared__ unsigned short As[BM * BK];  // 8 KB, [row][k] row-major
  __shared__ unsigned short Bs[BN * BK];  // 8 KB

  const int t = threadIdx.x;
  const int lane = t & 63;
  const int wave = t >> 6;
  const int wr = wave >> 1, wc = wave & 1;      // 2x2 wave grid, 64x64 each
  const int brow = blockIdx.y * BM;
  const int bcol = blockIdx.x * BN;

  // staging: load i = t + 256*j, row = i>>2, kchunk = i&3 (8 bf16 = 16B each)
  const int r0 = t >> 2, ch = t & 3;
  const long a_off0 = (long)(brow + r0) * K_DIM + ch * 8;
  const long a_off1 = (long)(brow + r0 + 64) * K_DIM + ch * 8;
  const long b_off0 = (long)(bcol + r0) * K_DIM + ch * 8;
  const long b_off1 = (long)(bcol + r0 + 64) * K_DIM + ch * 8;
  unsigned short* as_d0 = As + t * 8;
  unsigned short* as_d1 = As + (t + 256) * 8;
  unsigned short* bs_d0 = Bs + t * 8;
  unsigned short* bs_d1 = Bs + (t + 256) * 8;

  // fragment addressing: A/B row = lane&15, k = 8*(lane>>4)
  const int fr = lane & 15;
  const int kk = (lane >> 4) * 8;

  f32x4 acc[4][4] = {};

  for (int k0 = 0; k0 < K_DIM; k0 += BK) {
    gll16(A + a_off0 + k0, as_d0);
    gll16(A + a_off1 + k0, as_d1);
    gll16(Bw + b_off0 + k0, bs_d0);
    gll16(Bw + b_off1 + k0, bs_d1);
    __syncthreads();   // drains vmcnt before barrier -> LDS tiles ready

    bf16x8 af[4], bfr[4];
    #pragma unroll
    for (int m = 0; m < 4; ++m)
      af[m] = *reinterpret_cast<const bf16x8*>(&As[(wr * 64 + m * 16 + fr) * BK + kk]);
    #pragma unroll
    for (int n = 0; n < 4; ++n)
      bfr[n] = *reinterpret_cast<const bf16x8*>(&Bs[(wc * 64 + n * 16 + fr) * BK + kk]);

    #pragma unroll
    for (int m = 0; m < 4; ++m)
      #pragma unroll
      for (int n = 0; n < 4; ++n)
        acc[m][n] = __builtin_amdgcn_mfma_f32_16x16x32_bf16(af[m], bfr[n], acc[m][n], 0, 0, 0);

    __syncthreads();   // protect LDS before next stage overwrites
  }

  // epilogue: C/D layout col = lane&15, row = 4*(lane>>4) + reg  (m89-verified)
  const int crow0 = brow + wr * 64 + (lane >> 4) * 4;
  const int ccol0 = bcol + wc * 64 + fr;
  #pragma unroll
  for (int m = 0; m < 4; ++m) {
    #pragma unroll
    for (int n = 0; n < 4; ++n) {
      const int col = ccol0 + n * 16;
      const float bv = bias[col];
      #pragma unroll
      for (int r = 0; r < 4; ++r) {
        C[(long)(crow0 + m * 16 + r) * N_DIM + col] = acc[m][n][r] + bv;
      }
    }
  }
}

// ---------------- launch ----------------
extern "C" void kernel_launch(void* const* d_in, const int* in_sizes, int n_in,
                              void* d_out, int out_size, void* d_ws, size_t ws_size,
                              hipStream_t stream) {
  const float* x  = (const float*)d_in[0];   // [4,2048,4096]
  const float* W  = (const float*)d_in[1];   // [4096,4096]
  const float* bv = (const float*)d_in[2];   // [4096]
  const float* Am = (const float*)d_in[3];   // [8,16,4096]
  const float* Hm = (const float*)d_in[4];   // [8,16,16]
  const float* Bm = (const float*)d_in[5];   // [8,4096,16]
  const float* sv = (const float*)d_in[6];   // [8]
  float* out = (float*)d_out;                // [8192,4096]

  char* ws = (char*)d_ws;
  unsigned short* xbf  = (unsigned short*)ws;                       // 64 MB
  unsigned short* weff = (unsigned short*)(ws + (size_t)M_DIM * K_DIM * 2);  // 32 MB
  float* ha = (float*)(ws + (size_t)M_DIM * K_DIM * 2 + (size_t)N_DIM * K_DIM * 2); // 2 MB

  // 1) x -> bf16
  k_cast_bf16<<<(M_DIM * K_DIM / 4 + 255) / 256, 256, 0, stream>>>(x, xbf, M_DIM * K_DIM / 4);
  // 2) HA = s * (H @ A)
  k_ha<<<(NH * R_DIM * (K_DIM / 4)) / 256, 256, 0, stream>>>(Am, Hm, sv, ha);
  // 3) Weff = bf16(W + Bcat @ HA)
  k_weff<<<dim3(N_DIM / 8, 4), 256, 0, stream>>>(W, Bm, ha, weff);
  // 4) out = xbf @ Weff^T + b
  k_gemm<<<dim3(N_DIM / 128, M_DIM / 128), 256, 0, stream>>>(xbf, weff, bv, out);
}

// Round 3
// 360.911 us; speedup vs baseline: 1.2029x; 1.2029x over previous
//
#include <hip/hip_runtime.h>
#include <hip/hip_bf16.h>

typedef __attribute__((ext_vector_type(4))) float f32x4;
typedef __attribute__((ext_vector_type(8))) short bf16x8;

// Problem dims (fixed)
#define M_DIM 8192      // B*S = 4*2048
#define N_DIM 4096      // D_out
#define K_DIM 4096      // D_in
#define NH 8
#define R_DIM 16

__device__ __forceinline__ unsigned short f2bf(float f) {
  union { float f; unsigned int u; } v; v.f = f;
  unsigned int r = v.u + 0x7fffu + ((v.u >> 16) & 1u);  // RNE
  return (unsigned short)(r >> 16);
}

__device__ __forceinline__ void gll16(const void* gptr, void* lptr) {
  __builtin_amdgcn_global_load_lds(
      (const __attribute__((address_space(1))) void*)gptr,
      (__attribute__((address_space(3))) void*)lptr, 16, 0, 0);
}

#define FENCE() asm volatile("" ::: "memory")
#define BAR() do { FENCE(); __builtin_amdgcn_s_barrier(); FENCE(); } while (0)

// ---------------- Kernel 1: cast x (f32) -> bf16 ----------------
__global__ void k_cast_bf16(const float* __restrict__ in,
                            unsigned short* __restrict__ out, int n4) {
  int i = blockIdx.x * 256 + threadIdx.x;
  if (i >= n4) return;
  float4 v = reinterpret_cast<const float4*>(in)[i];
  ushort4 o;
  o.x = f2bf(v.x); o.y = f2bf(v.y); o.z = f2bf(v.z); o.w = f2bf(v.w);
  reinterpret_cast<ushort4*>(out)[i] = o;
}

// ---------------- Kernel 2: HA[h][q][d] = s[h] * sum_r H[h][q][r]*A[h][r][d] ----------------
__global__ void k_ha(const float* __restrict__ A, const float* __restrict__ H,
                     const float* __restrict__ s, float* __restrict__ HA) {
  int idx = blockIdx.x * 256 + threadIdx.x;   // 0 .. 131071
  int dc = idx & 1023;                        // float4 chunk
  int q  = (idx >> 10) & 15;
  int h  = idx >> 14;
  const float* Ah = A + (long)h * R_DIM * K_DIM;
  const float* Hh = H + h * R_DIM * R_DIM + q * R_DIM;
  f32x4 acc = {0.f, 0.f, 0.f, 0.f};
  #pragma unroll
  for (int r = 0; r < R_DIM; ++r) {
    float hv = Hh[r];
    float4 av = reinterpret_cast<const float4*>(Ah + (long)r * K_DIM)[dc];
    acc.x += hv * av.x; acc.y += hv * av.y; acc.z += hv * av.z; acc.w += hv * av.w;
  }
  float sv = s[h];
  float4 o; o.x = acc.x * sv; o.y = acc.y * sv; o.z = acc.z * sv; o.w = acc.w * sv;
  reinterpret_cast<float4*>(HA + ((long)h * R_DIM + q) * K_DIM)[dc] = o;
}

// ---------------- Kernel 3: Weff = bf16(W + Bcat @ HA) ----------------
__global__ void k_weff(const float* __restrict__ W, const float* __restrict__ Bm,
                       const float* __restrict__ HA, unsigned short* __restrict__ Weff) {
  __shared__ float bsh[8][128];
  int o0 = blockIdx.x * 8;
  int c4 = blockIdx.y * 256;   // float4 column base
  int t = threadIdx.x;
  for (int i = t; i < 1024; i += 256) {
    int r = i >> 7, hq = i & 127;
    int h = hq >> 4, q = hq & 15;
    bsh[r][hq] = Bm[((long)h * N_DIM + (o0 + r)) * R_DIM + q];
  }
  __syncthreads();
  int dc = c4 + t;
  f32x4 acc[8];
  #pragma unroll
  for (int r = 0; r < 8; ++r) {
    float4 w = reinterpret_cast<const float4*>(W + (long)(o0 + r) * K_DIM)[dc];
    acc[r].x = w.x; acc[r].y = w.y; acc[r].z = w.z; acc[r].w = w.w;
  }
  for (int hq = 0; hq < 128; ++hq) {
    float4 hv = reinterpret_cast<const float4*>(HA + (long)hq * K_DIM)[dc];
    #pragma unroll
    for (int r = 0; r < 8; ++r) {
      float bv = bsh[r][hq];
      acc[r].x += bv * hv.x; acc[r].y += bv * hv.y;
      acc[r].z += bv * hv.z; acc[r].w += bv * hv.w;
    }
  }
  #pragma unroll
  for (int r = 0; r < 8; ++r) {
    ushort4 ov;
    ov.x = f2bf(acc[r].x); ov.y = f2bf(acc[r].y);
    ov.z = f2bf(acc[r].z); ov.w = f2bf(acc[r].w);
    reinterpret_cast<ushort4*>(Weff + (long)(o0 + r) * K_DIM)[dc] = ov;
  }
}

// ---------------- Kernel 4: 256x256-tile 8-phase GEMM ----------------
// C[M][N] = Abf[M][K] @ Bbf[N][K]^T + bias.  BK=64, 512 thr (8 waves 2Mx4N).
// LDS: per operand 4 half-tile slots of 8192 elements ([128][64] bf16);
// tile T half h -> slot (T&1)*2+h.  Slot s = base + s*SLOT_E elements.
// Wave sub-tiles interleaved: phase quadrant (mh,nh) reads ONLY A-half mh, B-half nh.
// Stage order per tile: A0,B0,B1,A1 at 4-phase lookahead; vmcnt(6) at end of p3/p7.
// LDS swizzle: linear LDS dest + inverse-swizzled global source, byte ^= ((row&7)<<4).
__global__ __launch_bounds__(512, 2)
void k_gemm256(const unsigned short* __restrict__ A,   // x bf16 [M][K]
               const unsigned short* __restrict__ Bw,  // Weff bf16 [N][K]
               const float* __restrict__ bias,         // [N]
               float* __restrict__ C) {                // [M][N] f32
  __shared__ unsigned short As[4][128][64];  // 64 KB
  __shared__ unsigned short Bs[4][128][64];  // 64 KB
  constexpr int SLOT_E = 128 * 64;           // 8192 elements per slot (16 KB)

  const int t    = threadIdx.x;
  const int lane = t & 63;
  const int wave = t >> 6;
  const int wr   = wave >> 2;      // 0..1  (M sub-position within each 128-row half)
  const int wc   = wave & 3;       // 0..3  (N sub-position within each 128-col half)
  const int fr   = lane & 15;
  const int kq   = lane >> 4;      // 0..3

  // XCD-aware swizzle (nwg = 512, divisible by 8 -> simple bijective form)
  const int bid = blockIdx.x;
  const int swz = (bid & 7) * 64 + (bid >> 3);
  const int brow = (swz >> 4) * 256;   // 32 M-tiles
  const int bcol = (swz & 15) * 256;   // 16 N-tiles

  const unsigned short* Ag = A  + (size_t)brow * K_DIM;
  const unsigned short* Bg = Bw + (size_t)bcol * K_DIM;

  // staging: per thread 2x gll16 per half-tile; linear LDS dest i*16B,
  // i0 = t (rows 0..63), i1 = 512+t (rows 64..127); source col pre-swizzled.
  const int i0 = t, i1 = 512 + t;
  const int r_s0 = i0 >> 3, r_s1 = i1 >> 3;
  const int c_e0 = (((i0 & 7) * 16) ^ ((r_s0 & 7) << 4)) >> 1;   // element offset
  const int c_e1 = (((i1 & 7) * 16) ^ ((r_s1 & 7) << 4)) >> 1;

  unsigned short* as0 = &As[0][0][0];
  unsigned short* bs0 = &Bs[0][0][0];
  const char* lds_a = (const char*)as0;
  const char* lds_b = (const char*)bs0;

  // fragment read addressing (swizzled)
  const int arow = wr * 64 + fr;       // + m*16
  const int brow_l = wc * 32 + fr;     // + n*16
  const int axr = (fr & 7) << 4;       // XOR for both (row&7 == fr&7)

#define STAGE(DST, GBASE, T_, H_) do { \
    gll16((GBASE) + (size_t)((H_) * 128 + r_s0) * K_DIM + (T_) * 64 + c_e0, (DST) + i0 * 8); \
    gll16((GBASE) + (size_t)((H_) * 128 + r_s1) * K_DIM + (T_) * 64 + c_e1, (DST) + i1 * 8); \
  } while (0)

#define LOAD_A(SLOT) do { \
    _Pragma("unroll") for (int m = 0; m < 4; ++m) \
    _Pragma("unroll") for (int ks = 0; ks < 2; ++ks) \
      ar[m][ks] = *(const bf16x8*)(lds_a + (SLOT) * 16384 + (arow + m * 16) * 128 + ((kq * 16 + ks * 64) ^ axr)); \
  } while (0)

#define LOAD_B(SLOT, BR) do { \
    _Pragma("unroll") for (int n = 0; n < 2; ++n) \
    _Pragma("unroll") for (int ks = 0; ks < 2; ++ks) \
      BR[n][ks] = *(const bf16x8*)(lds_b + (SLOT) * 16384 + (brow_l + n * 16) * 128 + ((kq * 16 + ks * 64) ^ axr)); \
  } while (0)

#define MFMA_QUAD(MH, NHX, BR) do { \
    __builtin_amdgcn_s_setprio(1); \
    _Pragma("unroll") for (int m = 0; m < 4; ++m) \
    _Pragma("unroll") for (int n = 0; n < 2; ++n) \
    _Pragma("unroll") for (int ks = 0; ks < 2; ++ks) \
      acc[MH][NHX][m][n] = __builtin_amdgcn_mfma_f32_16x16x32_bf16(ar[m][ks], BR[n][ks], acc[MH][NHX][m][n], 0, 0, 0); \
    __builtin_amdgcn_s_setprio(0); \
  } while (0)

  bf16x8 ar[4][2];          // A fragments (reused across mh)
  bf16x8 b0r[2][2];         // B-half0 fragments (live p0-p2)
  bf16x8 b1r[2][2];         // B-half1 fragments (live p1-p3)
  f32x4 acc[2][2][4][2] = {};   // [mh][nh][m][n]

  // ---- prologue: tile0 (A0,B0,B1,A1) + tile1 (A0,B0,B1); A1(1) staged at p0.
  STAGE(as0 + 0 * SLOT_E, Ag, 0, 0);
  STAGE(bs0 + 0 * SLOT_E, Bg, 0, 0);
  STAGE(bs0 + 1 * SLOT_E, Bg, 0, 1);
  STAGE(as0 + 1 * SLOT_E, Ag, 0, 1);
  STAGE(as0 + 2 * SLOT_E, Ag, 1, 0);
  STAGE(bs0 + 2 * SLOT_E, Bg, 1, 0);
  STAGE(bs0 + 3 * SLOT_E, Bg, 1, 1);
  asm volatile("s_waitcnt vmcnt(6)" ::: "memory");   // tile0 fully resident
  __builtin_amdgcn_s_barrier();
  FENCE();

  #pragma unroll 1
  for (int it = 0; it < 31; ++it) {
    const int T = 2 * it;
    // p0: even q(0,0); stage A1(T+1)->A slot3
    LOAD_A(0); LOAD_B(0, b0r);
    STAGE(as0 + 3 * SLOT_E, Ag, T + 1, 1);
    BAR(); MFMA_QUAD(0, 0, b0r); BAR();
    // p1: even q(0,1); stage A0(T+2)->A slot0
    LOAD_B(1, b1r);
    STAGE(as0 + 0 * SLOT_E, Ag, T + 2, 0);
    BAR(); MFMA_QUAD(0, 1, b1r); BAR();
    // p2: even q(1,0); stage B0(T+2)->B slot0
    LOAD_A(1);
    STAGE(bs0 + 0 * SLOT_E, Bg, T + 2, 0);
    BAR(); MFMA_QUAD(1, 0, b0r); BAR();
    // p3: even q(1,1); stage B1(T+2)->B slot1; counted drain
    STAGE(bs0 + 1 * SLOT_E, Bg, T + 2, 1);
    BAR(); MFMA_QUAD(1, 1, b1r);
    asm volatile("s_waitcnt vmcnt(6)" ::: "memory");
    BAR();
    // p4: odd q(0,0); stage A1(T+2)->A slot1
    LOAD_A(2); LOAD_B(2, b0r);
    STAGE(as0 + 1 * SLOT_E, Ag, T + 2, 1);
    BAR(); MFMA_QUAD(0, 0, b0r); BAR();
    // p5: odd q(0,1); stage A0(T+3)->A slot2
    LOAD_B(3, b1r);
    STAGE(as0 + 2 * SLOT_E, Ag, T + 3, 0);
    BAR(); MFMA_QUAD(0, 1, b1r); BAR();
    // p6: odd q(1,0); stage B0(T+3)->B slot2
    LOAD_A(3);
    STAGE(bs0 + 2 * SLOT_E, Bg, T + 3, 0);
    BAR(); MFMA_QUAD(1, 0, b0r); BAR();
    // p7: odd q(1,1); stage B1(T+3)->B slot3; counted drain
    STAGE(bs0 + 3 * SLOT_E, Bg, T + 3, 1);
    BAR(); MFMA_QUAD(1, 1, b1r);
    asm volatile("s_waitcnt vmcnt(6)" ::: "memory");
    BAR();
  }

  // ---- epilogue: tiles 62 (slots 0,1) and 63 (slots 2,3); A1(63) still missing.
  STAGE(as0 + 3 * SLOT_E, Ag, 63, 1);
  asm volatile("s_waitcnt vmcnt(0)" ::: "memory");
  __builtin_amdgcn_s_barrier();
  FENCE();
  LOAD_A(0); LOAD_B(0, b0r); MFMA_QUAD(0, 0, b0r);
  LOAD_B(1, b1r);            MFMA_QUAD(0, 1, b1r);
  LOAD_A(1);                 MFMA_QUAD(1, 0, b0r);
                             MFMA_QUAD(1, 1, b1r);
  LOAD_A(2); LOAD_B(2, b0r); MFMA_QUAD(0, 0, b0r);
  LOAD_B(3, b1r);            MFMA_QUAD(0, 1, b1r);
  LOAD_A(3);                 MFMA_QUAD(1, 0, b0r);
                             MFMA_QUAD(1, 1, b1r);

#undef STAGE
#undef LOAD_A
#undef LOAD_B
#undef MFMA_QUAD

  // ---- C write: C/D layout col=lane&15, row=4*(lane>>4)+reg (m89-verified)
  const int crow = brow + wr * 64 + kq * 4;
  const int ccol = bcol + wc * 32 + fr;
  #pragma unroll
  for (int mh = 0; mh < 2; ++mh)
  #pragma unroll
  for (int nh = 0; nh < 2; ++nh)
  #pragma unroll
  for (int m = 0; m < 4; ++m)
  #pragma unroll
  for (int n = 0; n < 2; ++n) {
    const int col = ccol + nh * 128 + n * 16;
    const float bv = bias[col];
    #pragma unroll
    for (int r = 0; r < 4; ++r)
      C[(size_t)(crow + mh * 128 + m * 16 + r) * N_DIM + col] = acc[mh][nh][m][n][r] + bv;
  }
}

// ---------------- launch ----------------
extern "C" void kernel_launch(void* const* d_in, const int* in_sizes, int n_in,
                              void* d_out, int out_size, void* d_ws, size_t ws_size,
                              hipStream_t stream) {
  const float* x  = (const float*)d_in[0];   // [4,2048,4096]
  const float* W  = (const float*)d_in[1];   // [4096,4096]
  const float* bv = (const float*)d_in[2];   // [4096]
  const float* Am = (const float*)d_in[3];   // [8,16,4096]
  const float* Hm = (const float*)d_in[4];   // [8,16,16]
  const float* Bm = (const float*)d_in[5];   // [8,4096,16]
  const float* sv = (const float*)d_in[6];   // [8]
  float* out = (float*)d_out;                // [8192,4096]

  char* ws = (char*)d_ws;
  unsigned short* xbf  = (unsigned short*)ws;                                 // 64 MB
  unsigned short* weff = (unsigned short*)(ws + (size_t)M_DIM * K_DIM * 2);   // 32 MB
  float* ha = (float*)(ws + (size_t)M_DIM * K_DIM * 2 + (size_t)N_DIM * K_DIM * 2); // 2 MB

  k_cast_bf16<<<(M_DIM * K_DIM / 4 + 255) / 256, 256, 0, stream>>>(x, xbf, M_DIM * K_DIM / 4);
  k_ha<<<(NH * R_DIM * (K_DIM / 4)) / 256, 256, 0, stream>>>(Am, Hm, sv, ha);
  k_weff<<<dim3(N_DIM / 8, 4), 256, 0, stream>>>(W, Bm, ha, weff);
  k_gemm256<<<dim3(512), 512, 0, stream>>>(xbf, weff, bv, out);
}